// Round 1
// baseline (352.625 us; speedup 1.0000x reference)
//
#include <hip/hip_runtime.h>
#include <stdint.h>

typedef unsigned short u16;
typedef __bf16 bf16x8 __attribute__((ext_vector_type(8)));
typedef short s4 __attribute__((ext_vector_type(4)));
typedef float f32x4 __attribute__((ext_vector_type(4)));

#define B_ 2
#define S_ 2048
#define H_ 2048
#define NH_ 16
#define HD_ 128

// softmax scale folded with log2(e): exp(s*scale) == exp2(s*SL2)
#define SL2f (0.08838834764831845f * 1.4426950408889634f)

__device__ __forceinline__ u16 f2bf(float f) {
    uint32_t u = __float_as_uint(f);
    u += 0x7fff + ((u >> 16) & 1);  // round-to-nearest-even
    return (u16)(u >> 16);
}

// pack two f32 -> two bf16 (truncation) in ONE v_perm_b32 (P values in [0,1]; bias tiny)
__device__ __forceinline__ uint32_t pk_bf16(float lo, float hi) {
    return __builtin_amdgcn_perm(__float_as_uint(hi), __float_as_uint(lo), 0x07060302u);
}

// async global->LDS, 16B per lane, LDS dest = wave-uniform base + lane*16
__device__ __forceinline__ void gl_lds16(const u16* g, u16* l) {
    __builtin_amdgcn_global_load_lds(
        (const __attribute__((address_space(1))) void*)g,
        (__attribute__((address_space(3))) void*)l, 16, 0, 0);
}

union U2S4 { uint2 u; s4 s; };

// ---------------- prep: weight transpose+cast (z<4) and x cast (z==4) ----------------
__global__ __launch_bounds__(256) void prep_kernel(
        const float* __restrict__ x,
        const float* __restrict__ w0, const float* __restrict__ w1,
        const float* __restrict__ w2, const float* __restrict__ w3,
        u16* __restrict__ xb, u16* __restrict__ dqkv, u16* __restrict__ dwo) {
    int z = blockIdx.z;
    int tx = threadIdx.x, ty = threadIdx.y;  // 32 x 8
    if (z == 4) {
        // x cast: 4096 blocks x 2048 elems flat
        int tid = ty * 32 + tx;
        size_t base = ((size_t)(blockIdx.y * 64 + blockIdx.x)) * 2048 + tid * 8;
#pragma unroll
        for (int i = 0; i < 2; i++) {
            float4 v = *(const float4*)&x[base + i * 4];
            ushort4 o;
            o.x = f2bf(v.x); o.y = f2bf(v.y); o.z = f2bf(v.z); o.w = f2bf(v.w);
            *(ushort4*)&xb[base + i * 4] = o;
        }
        return;
    }
    const float* src = (z == 0) ? w0 : (z == 1) ? w1 : (z == 2) ? w2 : w3;
    u16* dst = (z < 3) ? (dqkv + (size_t)z * H_ * H_) : dwo;
    __shared__ float tile[32][33];
    int n0 = blockIdx.x * 32, k0 = blockIdx.y * 32;
#pragma unroll
    for (int i = 0; i < 4; i++)
        tile[ty + i * 8][tx] = src[(size_t)(k0 + ty + i * 8) * H_ + n0 + tx];
    __syncthreads();
#pragma unroll
    for (int i = 0; i < 4; i++)
        dst[(size_t)(n0 + ty + i * 8) * H_ + k0 + tx] = f2bf(tile[tx][ty + i * 8]);
}

// ---------------- GEMM: C[M,N] = A[M,K] @ Bt[N,K]^T  (bf16 in, fp32 acc) ----------------
// Pipelined rewrite (T3/T4 counted-vmcnt, no vmcnt(0) drain in the main loop):
//   BM=128, BN=256, BK=64, 512 threads = 8 waves as 2(M) x 4(N), per-wave 64x64 out.
//   LDS 128 KiB: A double-buffered (2 x 16 KiB), B triple-buffered (3 x 32 KiB).
//   Issue schedule per tile kt: A(kt+1) -> Abuf[(kt+1)&1], B(kt+2) -> Bbuf[(kt+2)%3].
//   Per-tile sync: s_waitcnt vmcnt(4) lgkmcnt(0); s_barrier.  Outstanding after wait =
//   B(kt+1)'s 4 loads (stay in flight across the barrier). vmcnt(0) only at kt=NT-1.
//   Hazards: lgkmcnt(0) at the top wait means every wave's ds_reads of a buffer are
//   complete before ANY wave passes the barrier after which that buffer is re-armed
//   (A period 2, B period 3 => writer is always >= 1 barrier after the last reader).
// MODE 0: N=6144 (Q|K|V). Q pre-scaled by SL2f -> Qb[b,h,s,d]; K -> Kbuf[b,h,s,d];
//         V-tiles transposed through LDS -> VT[b,h,d,s] with coalesced b128 stores.
// MODE 1: fp32 row-major output [M,N].
template <int MODE>
__global__ __launch_bounds__(512, 2) void gemm_bt(
        const u16* __restrict__ A, const u16* __restrict__ Bt, float* __restrict__ Cout,
        u16* __restrict__ q, u16* __restrict__ k, u16* __restrict__ v,
        int M, int N, int K) {
    // A bufs: sm + {0,1}*8192 ; B bufs: sm + 16384 + {0,1,2}*16384  (128 KiB total)
    __shared__ u16 sm[65536];
    int tid = threadIdx.x;
    int w = tid >> 6, lane = tid & 63, quad = lane >> 4, l16 = lane & 15;
    int wm = w >> 2, wn = w & 3;             // 2 x 4 wave grid
    int m0 = blockIdx.y * 128, n0 = blockIdx.x * 256;
    const int NT = K >> 6;                    // 64-wide K tiles

    f32x4 acc[4][4];
#pragma unroll
    for (int mi = 0; mi < 4; mi++)
#pragma unroll
        for (int ni = 0; ni < 4; ni++)
            acc[mi][ni] = (f32x4){0.f, 0.f, 0.f, 0.f};

    // A tile: 128x64 = 1024 16B-chunks, 2 per thread. Linear LDS dest, pre-swizzled src.
    auto stageA = [&](int kt) {
        const u16* ga = A + (size_t)m0 * K + kt * 64;
        u16* As = sm + (kt & 1) * 8192;
#pragma unroll
        for (int j = 0; j < 2; j++) {
            int p = j * 512 + tid;
            int row = p >> 3, c = (p & 7) ^ (row & 7);
            gl_lds16(&ga[(size_t)row * K + c * 8], &As[(j * 512 + w * 64) * 8]);
        }
    };
    // B tile: 256x64 = 2048 chunks, 4 per thread.
    auto stageB = [&](int kt) {
        const u16* gb = Bt + (size_t)n0 * K + kt * 64;
        u16* Bs = sm + 16384 + (kt % 3) * 16384;
#pragma unroll
        for (int j = 0; j < 4; j++) {
            int p = j * 512 + tid;
            int row = p >> 3, c = (p & 7) ^ (row & 7);
            gl_lds16(&gb[(size_t)row * K + c * 8], &Bs[(j * 512 + w * 64) * 8]);
        }
    };

    // prologue: A(0),B(0),B(1) issued (10 outstanding); A(1) comes from tile-0 body.
    stageA(0);
    stageB(0);
    stageB(1);

    for (int kt = 0; kt < NT; kt++) {
        __builtin_amdgcn_sched_barrier(0);
        if (kt == NT - 1)
            asm volatile("s_waitcnt vmcnt(0) lgkmcnt(0)" ::: "memory");
        else
            asm volatile("s_waitcnt vmcnt(4) lgkmcnt(0)" ::: "memory");
        __builtin_amdgcn_s_barrier();
        __builtin_amdgcn_sched_barrier(0);

        // prefetch issues first (DMA starts while we compute this tile)
        if (kt + 1 < NT) stageA(kt + 1);
        if (kt + 2 < NT) stageB(kt + 2);

        const u16* As = sm + (kt & 1) * 8192;
        const u16* Bs = sm + 16384 + (kt % 3) * 16384;
#pragma unroll
        for (int ks = 0; ks < 2; ks++) {
            bf16x8 af[4], bfr[4];
#pragma unroll
            for (int mi = 0; mi < 4; mi++) {
                int row = wm * 64 + mi * 16 + l16;
                af[mi] = *(const bf16x8*)&As[row * 64 + (((ks * 4 + quad) ^ (row & 7)) * 8)];
            }
#pragma unroll
            for (int ni = 0; ni < 4; ni++) {
                int row = wn * 64 + ni * 16 + l16;
                bfr[ni] = *(const bf16x8*)&Bs[row * 64 + (((ks * 4 + quad) ^ (row & 7)) * 8)];
            }
#pragma unroll
            for (int mi = 0; mi < 4; mi++)
#pragma unroll
                for (int ni = 0; ni < 4; ni++)
                    acc[mi][ni] = __builtin_amdgcn_mfma_f32_16x16x32_bf16(af[mi], bfr[ni], acc[mi][ni], 0, 0, 0);
        }
    }

    // epilogue: D layout col = lane&15, row = quad*4 + r (m89-verified)
    if (MODE == 0 && n0 >= 4096) {
        // ---- V tile: bounce through LDS (swizzled) and store VT[b,h,d,s] coalesced ----
        __syncthreads();             // all waves done reading A/B bufs before reuse
#pragma unroll
        for (int mi = 0; mi < 4; mi++) {
#pragma unroll
            for (int ni = 0; ni < 4; ni++) {
                int nl = wn * 64 + ni * 16 + l16;            // 0..255 (n = head dim pair)
#pragma unroll
                for (int r = 0; r < 4; r++) {
                    int ml = wm * 64 + mi * 16 + quad * 4 + r;  // 0..127 (m = seq)
                    sm[nl * 128 + (((ml >> 3) ^ (nl & 15)) * 8) + (ml & 7)] = f2bf(acc[mi][ni][r]);
                }
            }
        }
        __syncthreads();
        int b = m0 >> 11, s0 = m0 & 2047;
#pragma unroll
        for (int i = 0; i < 8; i++) {
            int cu = tid + i * 512;          // 4096 chunks: 256 rows x 16
            int nl = cu >> 4, mc = cu & 15;
            int4 val = *(const int4*)&sm[nl * 128 + ((mc ^ (nl & 15)) * 8)];
            int ngl = (n0 - 4096) + nl;
            int h = ngl >> 7, d = ngl & 127;
            *(int4*)&v[((size_t)((b * NH_ + h) * HD_ + d)) * S_ + s0 + mc * 8] = val;
        }
    } else {
#pragma unroll
        for (int mi = 0; mi < 4; mi++) {
#pragma unroll
            for (int ni = 0; ni < 4; ni++) {
                int ng = n0 + wn * 64 + ni * 16 + l16;
#pragma unroll
                for (int r = 0; r < 4; r++) {
                    int mg = m0 + wm * 64 + mi * 16 + quad * 4 + r;
                    float val = acc[mi][ni][r];
                    if (MODE == 0) {
                        int which = ng >> 11;          // 0=Q 1=K
                        int rem = ng & 2047;
                        int h = rem >> 7, d = rem & 127;
                        int b = mg >> 11, s = mg & 2047;
                        if (which == 0)
                            q[((size_t)((b * NH_ + h) * S_ + s)) * HD_ + d] = f2bf(val * SL2f);
                        else
                            k[((size_t)((b * NH_ + h) * S_ + s)) * HD_ + d] = f2bf(val);
                    } else {
                        Cout[(size_t)mg * N + ng] = val;
                    }
                }
            }
        }
    }
}

// ---------------- causal flash attention ----------------
// Paired q-tiles: 512 blocks, block (b,h,pair) does qt=pair then qt=31-pair -> uniform 33 iters.
// S^T = K·Q^T trick: P stays in registers (C-layout == B-frag of 16x16x16 MFMA).
// Barrier plan: phase1 = QK only (mid barrier drains lgkm only); K(t+1),V(t+1) DMA issued
// AFTER mid barrier, hidden under softmax+PV, drained at next top barrier. K,V both dbuf.
// LDS = 2*16K + 2*16K = 64KB -> exactly 2 blocks/CU for the 512-block grid.
__global__ __launch_bounds__(256, 2) void flash_kernel(
        const u16* __restrict__ Q, const u16* __restrict__ Kb,
        const u16* __restrict__ VT, u16* __restrict__ Ctx) {
    __shared__ u16 Ks[2][64 * 128];  // [kv][d], chunk c at c ^ (kv&15)
    __shared__ u16 Vs[2][128 * 64];  // [d][kv], chunk c at c ^ (d&7)
    int tid = threadIdx.x;
    int w = tid >> 6, lane = tid & 63, quad = lane >> 4, l16 = lane & 15;

    int id = blockIdx.x;
    int bh = id & 31;
    int b = bh >> 4, h = bh & 15;
    int pair = id >> 5;              // 0..15
    int qts = pair, qtl = 31 - pair;
    int n0 = qts + 1;                // iters in segment 0; total always 33

    size_t bhoff = ((size_t)b * NH_ + h) * S_ * HD_;
    const u16* Qp = Q + bhoff;
    const u16* Kp = Kb + bhoff;
    const u16* Vp = VT + bhoff;      // [d][s]

    auto stageK = [&](int t, int buf) {
        int kv0 = ((t >= n0) ? (t - n0) : t) * 64;
#pragma unroll
        for (int j = 0; j < 4; j++) {
            int base = (j * 4 + w) * 64;
            int p = base + lane;
            int row = p >> 4;
            int c = (p & 15) ^ (row & 15);
            gl_lds16(&Kp[(size_t)(kv0 + row) * HD_ + c * 8], &Ks[buf][base * 8]);
        }
    };
    auto stageV = [&](int t, int buf) {
        int kv0 = ((t >= n0) ? (t - n0) : t) * 64;
#pragma unroll
        for (int j = 0; j < 4; j++) {
            int base = (j * 4 + w) * 64;
            int p = base + lane;
            int row = p >> 3;
            int c = (p & 7) ^ (row & 7);
            gl_lds16(&Vp[(size_t)row * S_ + kv0 + c * 8], &Vs[buf][base * 8]);
        }
    };

    int q0 = qts * 64;
    int qg = q0 + w * 16 + l16;      // this lane's q row (S^T: lane = q column)
    bf16x8 qf[4];
#pragma unroll
    for (int ks = 0; ks < 4; ks++)
        qf[ks] = *(const bf16x8*)&Qp[(size_t)qg * HD_ + ks * 32 + quad * 8];

    float l_part = 0.f;
    f32x4 ao[8];                     // O^T acc: rows d=dt*16+quad*4+r, col q=l16
#pragma unroll
    for (int dt = 0; dt < 8; dt++) ao[dt] = (f32x4){0.f, 0.f, 0.f, 0.f};

    auto epilogue = [&]() {
        float l = l_part;
        l += __shfl_xor(l, 16);
        l += __shfl_xor(l, 32);
        float inv = 1.0f / l;
        size_t base = ((size_t)b * S_ + qg) * H_ + h * HD_;
#pragma unroll
        for (int dt = 0; dt < 8; dt++) {
            u16 o0 = f2bf(ao[dt][0] * inv), o1 = f2bf(ao[dt][1] * inv);
            u16 o2 = f2bf(ao[dt][2] * inv), o3 = f2bf(ao[dt][3] * inv);
            uint2 st;
            st.x = (uint32_t)o0 | ((uint32_t)o1 << 16);
            st.y = (uint32_t)o2 | ((uint32_t)o3 << 16);
            *(uint2*)&Ctx[base + dt * 16 + quad * 4] = st;
        }
    };

    stageK(0, 0);
    stageV(0, 0);

    for (int t = 0; t < 33; t++) {
        if (t == n0) {               // segment switch (PV of seg0 finished last iter)
            epilogue();
            q0 = qtl * 64;
            qg = q0 + w * 16 + l16;
#pragma unroll
            for (int ks = 0; ks < 4; ks++)
                qf[ks] = *(const bf16x8*)&Qp[(size_t)qg * HD_ + ks * 32 + quad * 8];
            l_part = 0.f;
#pragma unroll
            for (int dt = 0; dt < 8; dt++) ao[dt] = (f32x4){0.f, 0.f, 0.f, 0.f};
        }
        int buf = t & 1;
        __syncthreads();             // A: drains K(t),V(t) DMA (issued last phase-2)

        // --- phase 1: S^T = K·Q^T only (no vmem issued -> cheap mid barrier) ---
        f32x4 sc[4];
#pragma unroll
        for (int nt = 0; nt < 4; nt++) {
            sc[nt] = (f32x4){0.f, 0.f, 0.f, 0.f};
            int row = nt * 16 + l16;
#pragma unroll
            for (int ks = 0; ks < 4; ks++) {
                bf16x8 kf = *(const bf16x8*)&Ks[buf][row * 128 + (((ks * 4 + quad) ^ (row & 15)) * 8)];
                sc[nt] = __builtin_amdgcn_mfma_f32_16x16x32_bf16(kf, qf[ks], sc[nt], 0, 0, 0);
            }
        }

        __syncthreads();             // B: lgkm-only drain

        // --- phase 2: prefetch next K,V (hidden under softmax+PV, drained at next A) ---
        if (t + 1 < 33) {
            stageK(t + 1, buf ^ 1);
            stageV(t + 1, buf ^ 1);
        }

        // --- softmax in registers; pack P^T as 16x16x16 B-fragments ---
        bool diag = (t == n0 - 1) || (t == 32);
        U2S4 pk[4];
        if (!diag) {
#pragma unroll
            for (int nt = 0; nt < 4; nt++) {
                float p0 = exp2f(sc[nt][0]), p1 = exp2f(sc[nt][1]);
                float p2 = exp2f(sc[nt][2]), p3 = exp2f(sc[nt][3]);
                l_part += (p0 + p1) + (p2 + p3);
                pk[nt].u.x = pk_bf16(p0, p1);
                pk[nt].u.y = pk_bf16(p2, p3);
            }
        } else {                     // diagonal tile: causal mask (kv index vs qg)
            int kvb = q0 + quad * 4; // diag tile: kv0 == q0
#pragma unroll
            for (int nt = 0; nt < 4; nt++) {
                int kv = kvb + nt * 16;
                float p0 = (kv + 0 > qg) ? 0.f : exp2f(sc[nt][0]);
                float p1 = (kv + 1 > qg) ? 0.f : exp2f(sc[nt][1]);
                float p2 = (kv + 2 > qg) ? 0.f : exp2f(sc[nt][2]);
                float p3 = (kv + 3 > qg) ? 0.f : exp2f(sc[nt][3]);
                l_part += (p0 + p1) + (p2 + p3);
                pk[nt].u.x = pk_bf16(p0, p1);
                pk[nt].u.y = pk_bf16(p2, p3);
            }
        }

        // --- O^T += V^T·P^T : A=Vs[d][kv], B=pk (registers) ---
#pragma unroll
        for (int kt = 0; kt < 4; kt++) {
#pragma unroll
            for (int dt = 0; dt < 8; dt++) {
                int d = dt * 16 + l16;
                int c = kt * 2 + (quad >> 1);
                s4 va = *(const s4*)&Vs[buf][d * 64 + ((c ^ (d & 7)) * 8) + (quad & 1) * 4];
                ao[dt] = __builtin_amdgcn_mfma_f32_16x16x16bf16_1k(va, pk[kt].s, ao[dt], 0, 0, 0);
            }
        }
    }
    epilogue();
}

extern "C" void kernel_launch(void* const* d_in, const int* in_sizes, int n_in,
                              void* d_out, int out_size, void* d_ws, size_t ws_size,
                              hipStream_t stream) {
    const float* x  = (const float*)d_in[0];
    const float* Wq = (const float*)d_in[1];
    const float* Wk = (const float*)d_in[2];
    const float* Wv = (const float*)d_in[3];
    const float* Wo = (const float*)d_in[4];
    float* out = (float*)d_out;

    const size_t MB = 1024 * 1024;
    char* ws = (char*)d_ws;
    u16* Xb    = (u16*)(ws);            // 16 MB : x bf16 [4096,2048]
    u16* WqkvT = (u16*)(ws + 16 * MB);  // 24 MB : [6144,2048] (Wq^T;Wk^T;Wv^T)
    u16* WoT   = (u16*)(ws + 40 * MB);  //  8 MB
    u16* Qb    = (u16*)(ws + 48 * MB);  // 16 MB : [B,NH,S,HD], pre-scaled by SL2f
    u16* Kbuf  = (u16*)(ws + 64 * MB);  // 16 MB : [B,NH,S,HD]
    u16* VT    = (u16*)(ws + 80 * MB);  // 16 MB : [B,NH,HD,S]
    u16* Ctx   = (u16*)(ws + 96 * MB);  // 16 MB : [4096,2048]

    prep_kernel<<<dim3(64, 64, 5), dim3(32, 8), 0, stream>>>(x, Wq, Wk, Wv, Wo, Xb, WqkvT, WoT);
    // BM=128, BN=256: gemm0 grid 24x32 = 768 blocks = 3 exact CU-waves (1 blk/CU, 128KB LDS)
    gemm_bt<0><<<dim3(24, 32), 512, 0, stream>>>(Xb, WqkvT, nullptr, Qb, Kbuf, VT, 4096, 6144, 2048);
    flash_kernel<<<512, 256, 0, stream>>>(Qb, Kbuf, VT, Ctx);
    // gemm1 grid 8x32 = 256 blocks = 1 exact CU-wave
    gemm_bt<1><<<dim3(8, 32), 512, 0, stream>>>(Ctx, WoT, out, nullptr, nullptr, nullptr, 4096, 2048, 2048);
}

// Round 2
// 342.713 us; speedup vs baseline: 1.0289x; 1.0289x over previous
//
#include <hip/hip_runtime.h>
#include <stdint.h>

typedef unsigned short u16;
typedef __bf16 bf16x8 __attribute__((ext_vector_type(8)));
typedef short s4 __attribute__((ext_vector_type(4)));
typedef float f32x4 __attribute__((ext_vector_type(4)));

#define B_ 2
#define S_ 2048
#define H_ 2048
#define NH_ 16
#define HD_ 128

// softmax scale folded with log2(e): exp(s*scale) == exp2(s*SL2)
#define SL2f (0.08838834764831845f * 1.4426950408889634f)

__device__ __forceinline__ u16 f2bf(float f) {
    uint32_t u = __float_as_uint(f);
    u += 0x7fff + ((u >> 16) & 1);  // round-to-nearest-even
    return (u16)(u >> 16);
}

// pack two f32 -> two bf16 (truncation) in ONE v_perm_b32 (P values in [0,1]; bias tiny)
__device__ __forceinline__ uint32_t pk_bf16(float lo, float hi) {
    return __builtin_amdgcn_perm(__float_as_uint(hi), __float_as_uint(lo), 0x07060302u);
}

// async global->LDS, 16B per lane, LDS dest = wave-uniform base + lane*16
__device__ __forceinline__ void gl_lds16(const u16* g, u16* l) {
    __builtin_amdgcn_global_load_lds(
        (const __attribute__((address_space(1))) void*)g,
        (__attribute__((address_space(3))) void*)l, 16, 0, 0);
}

// phase-boundary sync: counted vmcnt (loads stay in flight), raw barrier, sched fences
__device__ __forceinline__ void sync_vm2() {
    __builtin_amdgcn_sched_barrier(0);
    asm volatile("s_waitcnt vmcnt(2)" ::: "memory");
    __builtin_amdgcn_s_barrier();
    __builtin_amdgcn_sched_barrier(0);
}
__device__ __forceinline__ void sync_vm0() {
    __builtin_amdgcn_sched_barrier(0);
    asm volatile("s_waitcnt vmcnt(0)" ::: "memory");
    __builtin_amdgcn_s_barrier();
    __builtin_amdgcn_sched_barrier(0);
}

union U2S4 { uint2 u; s4 s; };

// ---------------- prep: weight transpose+cast (z<4) and x cast (z==4) ----------------
__global__ __launch_bounds__(256) void prep_kernel(
        const float* __restrict__ x,
        const float* __restrict__ w0, const float* __restrict__ w1,
        const float* __restrict__ w2, const float* __restrict__ w3,
        u16* __restrict__ xb, u16* __restrict__ dqkv, u16* __restrict__ dwo) {
    int z = blockIdx.z;
    int tx = threadIdx.x, ty = threadIdx.y;  // 32 x 8
    if (z == 4) {
        // x cast: 4096 blocks x 2048 elems flat
        int tid = ty * 32 + tx;
        size_t base = ((size_t)(blockIdx.y * 64 + blockIdx.x)) * 2048 + tid * 8;
#pragma unroll
        for (int i = 0; i < 2; i++) {
            float4 v = *(const float4*)&x[base + i * 4];
            ushort4 o;
            o.x = f2bf(v.x); o.y = f2bf(v.y); o.z = f2bf(v.z); o.w = f2bf(v.w);
            *(ushort4*)&xb[base + i * 4] = o;
        }
        return;
    }
    const float* src = (z == 0) ? w0 : (z == 1) ? w1 : (z == 2) ? w2 : w3;
    u16* dst = (z < 3) ? (dqkv + (size_t)z * H_ * H_) : dwo;
    __shared__ float tile[32][33];
    int n0 = blockIdx.x * 32, k0 = blockIdx.y * 32;
#pragma unroll
    for (int i = 0; i < 4; i++)
        tile[ty + i * 8][tx] = src[(size_t)(k0 + ty + i * 8) * H_ + n0 + tx];
    __syncthreads();
#pragma unroll
    for (int i = 0; i < 4; i++)
        dst[(size_t)(n0 + ty + i * 8) * H_ + k0 + tx] = f2bf(tile[tx][ty + i * 8]);
}

// ---------------- QKV GEMM: phase-interleaved counted-vmcnt pipeline ----------------
// C[M,N] = A[M,K] @ Bt[N,K]^T, bf16 in, fp32 acc.  BM=128, BN=256, BK=64.
// 512 threads = 8 waves (2M x 4N), per-wave 64x64 output; acc[4][4] f32x4.
// LDS 96 KiB: A dbuf 2x16KB @0, B dbuf 2x32KB @16384(u16). 1 block/CU, grid = exact
// CU-waves (gemm0: 24x32 = 768 = 3.0 waves).
// Per K-tile, TWO phases (16 MFMA each, 2 barriers/phase-boundary):
//   P1: ds_read af(8)+bf_lo(4) | issue stageA(kt+1) | 16 MFMA (ni 0,1) | vmcnt(2)+bar
//   P2: ds_read bf_hi(4)       | issue stageB(kt+1) | 16 MFMA (ni 2,3) | vmcnt(2)+bar
// vmcnt ledger (per wave; issue order per tile = A'(2), B_lo'(2), B_hi'(2)):
//   entering kt P1: outstanding 6 = {A(kt),B(kt)}.. prior vmcnt(2) retired A(kt)+B_lo(kt)
//   end P1: outstanding {B_hi(kt),A(kt+1)}=4 -> vmcnt(2) retires B_hi(kt)   (P2 needs it)
//   end P2: outstanding {A(kt+1),B(kt+1)}=6 -> vmcnt(2) retires A(kt+1)+B_lo(kt+1)
// Loads are never drained to 0 in the loop (T4); last tile uses vmcnt(0) at end-P1.
// Hazard: a buffer region is DMA-overwritten only 2 barriers after its last ds_read,
// and every ds_read is drained by the data-dep waitcnt before its phase's MFMAs.
// Output (gemm0 layout): N=6144 as Q|K|V. Q pre-scaled by SL2f -> Qb[b,h,s,d];
// K -> Kbuf[b,h,s,d]; V-tiles transposed through LDS -> VT[b,h,d,s] (b128 stores).
__global__ __launch_bounds__(512, 2) void gemm_qkv(
        const u16* __restrict__ A, const u16* __restrict__ Bt,
        u16* __restrict__ q, u16* __restrict__ k, u16* __restrict__ v,
        int M, int N, int K) {
    __shared__ u16 sm[49152];  // 96 KiB
    int tid = threadIdx.x;
    int w = tid >> 6, lane = tid & 63, quad = lane >> 4, l16 = lane & 15;
    int wm = w >> 2, wn = w & 3;             // 2 x 4 wave grid
    int m0 = blockIdx.y * 128, n0 = blockIdx.x * 256;
    const int NT = K >> 6;

    f32x4 acc[4][4];
#pragma unroll
    for (int mi = 0; mi < 4; mi++)
#pragma unroll
        for (int ni = 0; ni < 4; ni++)
            acc[mi][ni] = (f32x4){0.f, 0.f, 0.f, 0.f};

    // A tile 128x64: 1024 chunks, 2/thread. Linear LDS dest, pre-swizzled source.
    auto stageA = [&](int kt) {
        const u16* ga = A + (size_t)m0 * K + kt * 64;
        u16* As = sm + (kt & 1) * 8192;
#pragma unroll
        for (int j = 0; j < 2; j++) {
            int p = j * 512 + tid;
            int row = p >> 3, c = (p & 7) ^ (row & 7);
            gl_lds16(&ga[(size_t)row * K + c * 8], &As[(j * 512 + w * 64) * 8]);
        }
    };
    // B tile 256x64: 2048 chunks, 4/thread; j=0,1 -> rows 0..127 (B_lo), j=2,3 -> B_hi.
    auto stageB = [&](int kt) {
        const u16* gb = Bt + (size_t)n0 * K + kt * 64;
        u16* Bs = sm + 16384 + (kt & 1) * 16384;
#pragma unroll
        for (int j = 0; j < 4; j++) {
            int p = j * 512 + tid;
            int row = p >> 3, c = (p & 7) ^ (row & 7);
            gl_lds16(&gb[(size_t)row * K + c * 8], &Bs[(j * 512 + w * 64) * 8]);
        }
    };

    // prologue: tile 0 staged; vmcnt(2) retires A(0)+B_lo(0) (exactly what P1 reads)
    stageA(0);
    stageB(0);
    sync_vm2();

    for (int kt = 0; kt < NT; kt++) {
        bool lastT = (kt == NT - 1);
        const u16* Ab = sm + (kt & 1) * 8192;
        const u16* Bb = sm + 16384 + (kt & 1) * 16384;

        // ---- phase 1: quadrant ni={0,1} ----
        bf16x8 af[2][4], bfl[2][2];
#pragma unroll
        for (int ks = 0; ks < 2; ks++)
#pragma unroll
            for (int mi = 0; mi < 4; mi++) {
                int row = wm * 64 + mi * 16 + l16;
                af[ks][mi] = *(const bf16x8*)&Ab[row * 64 + (((ks * 4 + quad) ^ (row & 7)) * 8)];
            }
#pragma unroll
        for (int ks = 0; ks < 2; ks++)
#pragma unroll
            for (int ni = 0; ni < 2; ni++) {
                int row = wn * 32 + ni * 16 + l16;
                bfl[ks][ni] = *(const bf16x8*)&Bb[row * 64 + (((ks * 4 + quad) ^ (row & 7)) * 8)];
            }
        if (!lastT) stageA(kt + 1);
        __builtin_amdgcn_s_setprio(1);
#pragma unroll
        for (int ks = 0; ks < 2; ks++)
#pragma unroll
            for (int mi = 0; mi < 4; mi++)
#pragma unroll
                for (int ni = 0; ni < 2; ni++)
                    acc[mi][ni] = __builtin_amdgcn_mfma_f32_16x16x32_bf16(af[ks][mi], bfl[ks][ni], acc[mi][ni], 0, 0, 0);
        __builtin_amdgcn_s_setprio(0);
        if (!lastT) sync_vm2();   // retires B_hi(kt) for P2
        else sync_vm0();

        // ---- phase 2: quadrant ni={2,3} (reuses af) ----
        bf16x8 bfh[2][2];
#pragma unroll
        for (int ks = 0; ks < 2; ks++)
#pragma unroll
            for (int ni = 0; ni < 2; ni++) {
                int row = 128 + wn * 32 + ni * 16 + l16;
                bfh[ks][ni] = *(const bf16x8*)&Bb[row * 64 + (((ks * 4 + quad) ^ (row & 7)) * 8)];
            }
        if (!lastT) stageB(kt + 1);
        __builtin_amdgcn_s_setprio(1);
#pragma unroll
        for (int ks = 0; ks < 2; ks++)
#pragma unroll
            for (int mi = 0; mi < 4; mi++)
#pragma unroll
                for (int ni = 0; ni < 2; ni++)
                    acc[mi][ni + 2] = __builtin_amdgcn_mfma_f32_16x16x32_bf16(af[ks][mi], bfh[ks][ni], acc[mi][ni + 2], 0, 0, 0);
        __builtin_amdgcn_s_setprio(0);
        if (!lastT) sync_vm2();   // retires A(kt+1)+B_lo(kt+1) for next P1
    }

    // epilogue: D layout col = lane&15, row = quad*4 + r (m89-verified)
    // per-wave cols: ng = n0 + (ni>>1)*128 + wn*32 + (ni&1)*16 + l16
    // per-wave rows: mg = m0 + wm*64 + mi*16 + quad*4 + r
    if (n0 >= 4096) {
        // ---- V tile (256n x 128m): bounce through LDS, store VT[b,h,d,s] coalesced ----
        // scratch [0, 32768) u16 is disjoint from B buf1 [32768,49152) (the only region
        // still being read by trailing waves in the last P2) -> no barrier needed first.
#pragma unroll
        for (int mi = 0; mi < 4; mi++) {
#pragma unroll
            for (int ni = 0; ni < 4; ni++) {
                int nl = (ni >> 1) * 128 + wn * 32 + (ni & 1) * 16 + l16;  // 0..255
#pragma unroll
                for (int r = 0; r < 4; r++) {
                    int ml = wm * 64 + mi * 16 + quad * 4 + r;             // 0..127
                    sm[nl * 128 + (((ml >> 3) ^ (nl & 15)) * 8) + (ml & 7)] = f2bf(acc[mi][ni][r]);
                }
            }
        }
        __syncthreads();
        int b = m0 >> 11, s0 = m0 & 2047;
#pragma unroll
        for (int i = 0; i < 8; i++) {
            int cu = tid + i * 512;          // 4096 chunks: 256 rows x 16
            int nl = cu >> 4, mc = cu & 15;
            int4 val = *(const int4*)&sm[nl * 128 + ((mc ^ (nl & 15)) * 8)];
            int ngl = (n0 - 4096) + nl;
            int h = ngl >> 7, d = ngl & 127;
            *(int4*)&v[((size_t)((b * NH_ + h) * HD_ + d)) * S_ + s0 + mc * 8] = val;
        }
    } else {
#pragma unroll
        for (int mi = 0; mi < 4; mi++) {
#pragma unroll
            for (int ni = 0; ni < 4; ni++) {
                int ng = n0 + (ni >> 1) * 128 + wn * 32 + (ni & 1) * 16 + l16;
                int which = ng >> 11;          // 0=Q 1=K
                int rem = ng & 2047;
                int h = rem >> 7, d = rem & 127;
#pragma unroll
                for (int r = 0; r < 4; r++) {
                    int mg = m0 + wm * 64 + mi * 16 + quad * 4 + r;
                    float val = acc[mi][ni][r];
                    int b = mg >> 11, s = mg & 2047;
                    if (which == 0)
                        q[((size_t)((b * NH_ + h) * S_ + s)) * HD_ + d] = f2bf(val * SL2f);
                    else
                        k[((size_t)((b * NH_ + h) * S_ + s)) * HD_ + d] = f2bf(val);
                }
            }
        }
    }
}

// ---------------- output GEMM (round-0 proven 128x128 structure, MODE 1 only) --------
// C[M,N] = A[M,K] @ Bt[N,K]^T, fp32 row-major output.
__global__ __launch_bounds__(256, 2) void gemm_out(
        const u16* __restrict__ A, const u16* __restrict__ Bt, float* __restrict__ Cout,
        int M, int N, int K) {
    __shared__ u16 sm[2 * 128 * 64];   // As | Bs
    u16* As = sm;
    u16* Bs = sm + 128 * 64;
    int tid = threadIdx.x;
    int w = tid >> 6, lane = tid & 63, quad = lane >> 4, l16 = lane & 15;
    int wm = w >> 1, wn = w & 1;
    int m0 = blockIdx.y * 128, n0 = blockIdx.x * 128;

    f32x4 acc[4][4];
#pragma unroll
    for (int mi = 0; mi < 4; mi++)
#pragma unroll
        for (int ni = 0; ni < 4; ni++)
            acc[mi][ni] = (f32x4){0.f, 0.f, 0.f, 0.f};

    for (int k0 = 0; k0 < K; k0 += 64) {
        const u16* ga = A + (size_t)m0 * K + k0;
        const u16* gb = Bt + (size_t)n0 * K + k0;
#pragma unroll
        for (int j = 0; j < 4; j++) {
            int base = (j * 4 + w) * 64;
            int p = base + lane;
            int row = p >> 3;
            int c = (p & 7) ^ (row & 7);
            gl_lds16(&ga[(size_t)row * K + c * 8], &As[base * 8]);
            gl_lds16(&gb[(size_t)row * K + c * 8], &Bs[base * 8]);
        }
        __syncthreads();
#pragma unroll
        for (int ks = 0; ks < 2; ks++) {
            bf16x8 af[4], bfr[4];
#pragma unroll
            for (int mi = 0; mi < 4; mi++) {
                int row = wm * 64 + mi * 16 + l16;
                af[mi] = *(const bf16x8*)&As[row * 64 + (((ks * 4 + quad) ^ (row & 7)) * 8)];
            }
#pragma unroll
            for (int ni = 0; ni < 4; ni++) {
                int row = wn * 64 + ni * 16 + l16;
                bfr[ni] = *(const bf16x8*)&Bs[row * 64 + (((ks * 4 + quad) ^ (row & 7)) * 8)];
            }
#pragma unroll
            for (int mi = 0; mi < 4; mi++)
#pragma unroll
                for (int ni = 0; ni < 4; ni++)
                    acc[mi][ni] = __builtin_amdgcn_mfma_f32_16x16x32_bf16(af[mi], bfr[ni], acc[mi][ni], 0, 0, 0);
        }
        __syncthreads();
    }

#pragma unroll
    for (int mi = 0; mi < 4; mi++) {
#pragma unroll
        for (int ni = 0; ni < 4; ni++) {
            int ng = n0 + wn * 64 + ni * 16 + l16;
#pragma unroll
            for (int r = 0; r < 4; r++) {
                int mg = m0 + wm * 64 + mi * 16 + quad * 4 + r;
                Cout[(size_t)mg * N + ng] = acc[mi][ni][r];
            }
        }
    }
}

// ---------------- causal flash attention ----------------
// Paired q-tiles: 512 blocks, block (b,h,pair) does qt=pair then qt=31-pair -> uniform 33 iters.
// S^T = K·Q^T trick: P stays in registers (C-layout == B-frag of 16x16x16 MFMA).
// Barrier plan: phase1 = QK only (mid barrier drains lgkm only); K(t+1),V(t+1) DMA issued
// AFTER mid barrier, hidden under softmax+PV, drained at next top barrier. K,V both dbuf.
// LDS = 2*16K + 2*16K = 64KB -> exactly 2 blocks/CU for the 512-block grid.
__global__ __launch_bounds__(256, 2) void flash_kernel(
        const u16* __restrict__ Q, const u16* __restrict__ Kb,
        const u16* __restrict__ VT, u16* __restrict__ Ctx) {
    __shared__ u16 Ks[2][64 * 128];  // [kv][d], chunk c at c ^ (kv&15)
    __shared__ u16 Vs[2][128 * 64];  // [d][kv], chunk c at c ^ (d&7)
    int tid = threadIdx.x;
    int w = tid >> 6, lane = tid & 63, quad = lane >> 4, l16 = lane & 15;

    int id = blockIdx.x;
    int bh = id & 31;
    int b = bh >> 4, h = bh & 15;
    int pair = id >> 5;              // 0..15
    int qts = pair, qtl = 31 - pair;
    int n0 = qts + 1;                // iters in segment 0; total always 33

    size_t bhoff = ((size_t)b * NH_ + h) * S_ * HD_;
    const u16* Qp = Q + bhoff;
    const u16* Kp = Kb + bhoff;
    const u16* Vp = VT + bhoff;      // [d][s]

    auto stageK = [&](int t, int buf) {
        int kv0 = ((t >= n0) ? (t - n0) : t) * 64;
#pragma unroll
        for (int j = 0; j < 4; j++) {
            int base = (j * 4 + w) * 64;
            int p = base + lane;
            int row = p >> 4;
            int c = (p & 15) ^ (row & 15);
            gl_lds16(&Kp[(size_t)(kv0 + row) * HD_ + c * 8], &Ks[buf][base * 8]);
        }
    };
    auto stageV = [&](int t, int buf) {
        int kv0 = ((t >= n0) ? (t - n0) : t) * 64;
#pragma unroll
        for (int j = 0; j < 4; j++) {
            int base = (j * 4 + w) * 64;
            int p = base + lane;
            int row = p >> 3;
            int c = (p & 7) ^ (row & 7);
            gl_lds16(&Vp[(size_t)row * S_ + kv0 + c * 8], &Vs[buf][base * 8]);
        }
    };

    int q0 = qts * 64;
    int qg = q0 + w * 16 + l16;      // this lane's q row (S^T: lane = q column)
    bf16x8 qf[4];
#pragma unroll
    for (int ks = 0; ks < 4; ks++)
        qf[ks] = *(const bf16x8*)&Qp[(size_t)qg * HD_ + ks * 32 + quad * 8];

    float l_part = 0.f;
    f32x4 ao[8];                     // O^T acc: rows d=dt*16+quad*4+r, col q=l16
#pragma unroll
    for (int dt = 0; dt < 8; dt++) ao[dt] = (f32x4){0.f, 0.f, 0.f, 0.f};

    auto epilogue = [&]() {
        float l = l_part;
        l += __shfl_xor(l, 16);
        l += __shfl_xor(l, 32);
        float inv = 1.0f / l;
        size_t base = ((size_t)b * S_ + qg) * H_ + h * HD_;
#pragma unroll
        for (int dt = 0; dt < 8; dt++) {
            u16 o0 = f2bf(ao[dt][0] * inv), o1 = f2bf(ao[dt][1] * inv);
            u16 o2 = f2bf(ao[dt][2] * inv), o3 = f2bf(ao[dt][3] * inv);
            uint2 st;
            st.x = (uint32_t)o0 | ((uint32_t)o1 << 16);
            st.y = (uint32_t)o2 | ((uint32_t)o3 << 16);
            *(uint2*)&Ctx[base + dt * 16 + quad * 4] = st;
        }
    };

    stageK(0, 0);
    stageV(0, 0);

    for (int t = 0; t < 33; t++) {
        if (t == n0) {               // segment switch (PV of seg0 finished last iter)
            epilogue();
            q0 = qtl * 64;
            qg = q0 + w * 16 + l16;
#pragma unroll
            for (int ks = 0; ks < 4; ks++)
                qf[ks] = *(const bf16x8*)&Qp[(size_t)qg * HD_ + ks * 32 + quad * 8];
            l_part = 0.f;
#pragma unroll
            for (int dt = 0; dt < 8; dt++) ao[dt] = (f32x4){0.f, 0.f, 0.f, 0.f};
        }
        int buf = t & 1;
        __syncthreads();             // A: drains K(t),V(t) DMA (issued last phase-2)

        // --- phase 1: S^T = K·Q^T only (no vmem issued -> cheap mid barrier) ---
        f32x4 sc[4];
#pragma unroll
        for (int nt = 0; nt < 4; nt++) {
            sc[nt] = (f32x4){0.f, 0.f, 0.f, 0.f};
            int row = nt * 16 + l16;
#pragma unroll
            for (int ks = 0; ks < 4; ks++) {
                bf16x8 kf = *(const bf16x8*)&Ks[buf][row * 128 + (((ks * 4 + quad) ^ (row & 15)) * 8)];
                sc[nt] = __builtin_amdgcn_mfma_f32_16x16x32_bf16(kf, qf[ks], sc[nt], 0, 0, 0);
            }
        }

        __syncthreads();             // B: lgkm-only drain

        // --- phase 2: prefetch next K,V (hidden under softmax+PV, drained at next A) ---
        if (t + 1 < 33) {
            stageK(t + 1, buf ^ 1);
            stageV(t + 1, buf ^ 1);
        }

        // --- softmax in registers; pack P^T as 16x16x16 B-fragments ---
        bool diag = (t == n0 - 1) || (t == 32);
        U2S4 pk[4];
        if (!diag) {
#pragma unroll
            for (int nt = 0; nt < 4; nt++) {
                float p0 = exp2f(sc[nt][0]), p1 = exp2f(sc[nt][1]);
                float p2 = exp2f(sc[nt][2]), p3 = exp2f(sc[nt][3]);
                l_part += (p0 + p1) + (p2 + p3);
                pk[nt].u.x = pk_bf16(p0, p1);
                pk[nt].u.y = pk_bf16(p2, p3);
            }
        } else {                     // diagonal tile: causal mask (kv index vs qg)
            int kvb = q0 + quad * 4; // diag tile: kv0 == q0
#pragma unroll
            for (int nt = 0; nt < 4; nt++) {
                int kv = kvb + nt * 16;
                float p0 = (kv + 0 > qg) ? 0.f : exp2f(sc[nt][0]);
                float p1 = (kv + 1 > qg) ? 0.f : exp2f(sc[nt][1]);
                float p2 = (kv + 2 > qg) ? 0.f : exp2f(sc[nt][2]);
                float p3 = (kv + 3 > qg) ? 0.f : exp2f(sc[nt][3]);
                l_part += (p0 + p1) + (p2 + p3);
                pk[nt].u.x = pk_bf16(p0, p1);
                pk[nt].u.y = pk_bf16(p2, p3);
            }
        }

        // --- O^T += V^T·P^T : A=Vs[d][kv], B=pk (registers) ---
#pragma unroll
        for (int kt = 0; kt < 4; kt++) {
#pragma unroll
            for (int dt = 0; dt < 8; dt++) {
                int d = dt * 16 + l16;
                int c = kt * 2 + (quad >> 1);
                s4 va = *(const s4*)&Vs[buf][d * 64 + ((c ^ (d & 7)) * 8) + (quad & 1) * 4];
                ao[dt] = __builtin_amdgcn_mfma_f32_16x16x16bf16_1k(va, pk[kt].s, ao[dt], 0, 0, 0);
            }
        }
    }
    epilogue();
}

extern "C" void kernel_launch(void* const* d_in, const int* in_sizes, int n_in,
                              void* d_out, int out_size, void* d_ws, size_t ws_size,
                              hipStream_t stream) {
    const float* x  = (const float*)d_in[0];
    const float* Wq = (const float*)d_in[1];
    const float* Wk = (const float*)d_in[2];
    const float* Wv = (const float*)d_in[3];
    const float* Wo = (const float*)d_in[4];
    float* out = (float*)d_out;

    const size_t MB = 1024 * 1024;
    char* ws = (char*)d_ws;
    u16* Xb    = (u16*)(ws);            // 16 MB : x bf16 [4096,2048]
    u16* WqkvT = (u16*)(ws + 16 * MB);  // 24 MB : [6144,2048] (Wq^T;Wk^T;Wv^T)
    u16* WoT   = (u16*)(ws + 40 * MB);  //  8 MB
    u16* Qb    = (u16*)(ws + 48 * MB);  // 16 MB : [B,NH,S,HD], pre-scaled by SL2f
    u16* Kbuf  = (u16*)(ws + 64 * MB);  // 16 MB : [B,NH,S,HD]
    u16* VT    = (u16*)(ws + 80 * MB);  // 16 MB : [B,NH,HD,S]
    u16* Ctx   = (u16*)(ws + 96 * MB);  // 16 MB : [4096,2048]

    prep_kernel<<<dim3(64, 64, 5), dim3(32, 8), 0, stream>>>(x, Wq, Wk, Wv, Wo, Xb, WqkvT, WoT);
    // phase-pipelined QKV GEMM: 24x32 = 768 blocks = 3.0 exact CU-waves (1 blk/CU)
    gemm_qkv<<<dim3(24, 32), 512, 0, stream>>>(Xb, WqkvT, Qb, Kbuf, VT, 4096, 6144, 2048);
    flash_kernel<<<512, 256, 0, stream>>>(Qb, Kbuf, VT, Ctx);
    // output GEMM: round-0 proven 128^2 structure, 16x32 = 512 blocks
    gemm_out<<<dim3(16, 32), 256, 0, stream>>>(Ctx, WoT, out, 4096, 2048, 2048);
}

// Round 3
// 340.561 us; speedup vs baseline: 1.0354x; 1.0063x over previous
//
#include <hip/hip_runtime.h>
#include <stdint.h>

typedef unsigned short u16;
typedef __bf16 bf16x8 __attribute__((ext_vector_type(8)));
typedef short s4 __attribute__((ext_vector_type(4)));
typedef float f32x4 __attribute__((ext_vector_type(4)));

#define B_ 2
#define S_ 2048
#define H_ 2048
#define NH_ 16
#define HD_ 128

// softmax scale folded with log2(e): exp(s*scale) == exp2(s*SL2)
#define SL2f (0.08838834764831845f * 1.4426950408889634f)

__device__ __forceinline__ u16 f2bf(float f) {
    uint32_t u = __float_as_uint(f);
    u += 0x7fff + ((u >> 16) & 1);  // round-to-nearest-even
    return (u16)(u >> 16);
}

// pack two f32 -> two bf16 (truncation) in ONE v_perm_b32 (P values in [0,1]; bias tiny)
__device__ __forceinline__ uint32_t pk_bf16(float lo, float hi) {
    return __builtin_amdgcn_perm(__float_as_uint(hi), __float_as_uint(lo), 0x07060302u);
}

// async global->LDS, 16B per lane, LDS dest = wave-uniform base + lane*16
__device__ __forceinline__ void gl_lds16(const u16* g, u16* l) {
    __builtin_amdgcn_global_load_lds(
        (const __attribute__((address_space(1))) void*)g,
        (__attribute__((address_space(3))) void*)l, 16, 0, 0);
}

union U2S4 { uint2 u; s4 s; };

// ---------------- prep: weight transpose+cast (z<4) and x cast (z==4) ----------------
__global__ __launch_bounds__(256) void prep_kernel(
        const float* __restrict__ x,
        const float* __restrict__ w0, const float* __restrict__ w1,
        const float* __restrict__ w2, const float* __restrict__ w3,
        u16* __restrict__ xb, u16* __restrict__ dqkv, u16* __restrict__ dwo) {
    int z = blockIdx.z;
    int tx = threadIdx.x, ty = threadIdx.y;  // 32 x 8
    if (z == 4) {
        // x cast: 4096 blocks x 2048 elems flat
        int tid = ty * 32 + tx;
        size_t base = ((size_t)(blockIdx.y * 64 + blockIdx.x)) * 2048 + tid * 8;
#pragma unroll
        for (int i = 0; i < 2; i++) {
            float4 v = *(const float4*)&x[base + i * 4];
            ushort4 o;
            o.x = f2bf(v.x); o.y = f2bf(v.y); o.z = f2bf(v.z); o.w = f2bf(v.w);
            *(ushort4*)&xb[base + i * 4] = o;
        }
        return;
    }
    const float* src = (z == 0) ? w0 : (z == 1) ? w1 : (z == 2) ? w2 : w3;
    u16* dst = (z < 3) ? (dqkv + (size_t)z * H_ * H_) : dwo;
    __shared__ float tile[32][33];
    int n0 = blockIdx.x * 32, k0 = blockIdx.y * 32;
#pragma unroll
    for (int i = 0; i < 4; i++)
        tile[ty + i * 8][tx] = src[(size_t)(k0 + ty + i * 8) * H_ + n0 + tx];
    __syncthreads();
#pragma unroll
    for (int i = 0; i < 4; i++)
        dst[(size_t)(n0 + ty + i * 8) * H_ + k0 + tx] = f2bf(tile[tx][ty + i * 8]);
}

// ---------------- QKV GEMM: fat-wave-tile, round-0 schedule ----------------
// C[M,N] = A[M,K] @ Bt[N,K]^T, bf16 in, fp32 acc.
// Geometry: BM=128, BN=192, BK=64; 256 thr = 4 waves (2M x 2N); per-wave 64x96
// (acc[4][6], 96 VGPR). LDS-fragment-read model: per wave per K-tile 20 b128 reads
// feed 48 MFMA -> per-CU (2 blocks) LDS 160 KB (~625cy) vs MFMA 96/SIMD (~461cy)
// -> MfmaUtil ceiling ~74% (round-0 64x64 geometry: 60%, measured 45%).
// Schedule: round-0 proven single-buffer {stage -> sync -> compute -> sync}.
// LDS 40 KB used, PADDED to 56 KB to pin exactly 2 blocks/CU: grid 32x32 = 1024
// blocks = exactly 2.0 residency rounds, zero tail (vs m201 256^2: 384 blk = 1.5).
// Output: N=6144 as Q|K|V. Q pre-scaled by SL2f -> Qb[b,h,s,d]; K -> Kbuf[b,h,s,d];
// V via LDS bounce -> VT[b,h,d,s] b128 stores. BN=192 => tile bx=21 straddles the
// K/V boundary at n=4096: scalar path covers ng<4096, bounce covers nl >= 4096-n0.
__global__ __launch_bounds__(256, 2) void gemm_qkv(
        const u16* __restrict__ A, const u16* __restrict__ Bt,
        u16* __restrict__ q, u16* __restrict__ k, u16* __restrict__ v,
        int M, int N, int K) {
    __shared__ u16 sm[28672];           // 56 KB alloc; 40 KB used (As 16K | Bs 24K)
    u16* As = sm;                        // [128][64] chunk-swizzled
    u16* Bs = sm + 8192;                 // [192][64] chunk-swizzled
    int tid = threadIdx.x;
    int w = tid >> 6, lane = tid & 63, quad = lane >> 4, l16 = lane & 15;
    int wm = w >> 1, wn = w & 1;         // 2 x 2 wave grid
    int m0 = blockIdx.y * 128, n0 = blockIdx.x * 192;

    f32x4 acc[4][6];
#pragma unroll
    for (int mi = 0; mi < 4; mi++)
#pragma unroll
        for (int ni = 0; ni < 6; ni++)
            acc[mi][ni] = (f32x4){0.f, 0.f, 0.f, 0.f};

    for (int k0 = 0; k0 < K; k0 += 64) {
        const u16* ga = A + (size_t)m0 * K + k0;
        const u16* gb = Bt + (size_t)n0 * K + k0;
        // A: 128x64 = 1024 chunks (4/thread); B: 192x64 = 1536 chunks (6/thread)
#pragma unroll
        for (int j = 0; j < 4; j++) {
            int p = j * 256 + tid;
            int row = p >> 3, c = (p & 7) ^ (row & 7);
            gl_lds16(&ga[(size_t)row * K + c * 8], &As[(j * 256 + w * 64) * 8]);
        }
#pragma unroll
        for (int j = 0; j < 6; j++) {
            int p = j * 256 + tid;
            int row = p >> 3, c = (p & 7) ^ (row & 7);
            gl_lds16(&gb[(size_t)row * K + c * 8], &Bs[(j * 256 + w * 64) * 8]);
        }
        __syncthreads();
#pragma unroll
        for (int ks = 0; ks < 2; ks++) {
            bf16x8 af[4], bfr[6];
#pragma unroll
            for (int mi = 0; mi < 4; mi++) {
                int row = wm * 64 + mi * 16 + l16;
                af[mi] = *(const bf16x8*)&As[row * 64 + (((ks * 4 + quad) ^ (row & 7)) * 8)];
            }
#pragma unroll
            for (int ni = 0; ni < 6; ni++) {
                int row = wn * 96 + ni * 16 + l16;
                bfr[ni] = *(const bf16x8*)&Bs[row * 64 + (((ks * 4 + quad) ^ (row & 7)) * 8)];
            }
#pragma unroll
            for (int mi = 0; mi < 4; mi++)
#pragma unroll
                for (int ni = 0; ni < 6; ni++)
                    acc[mi][ni] = __builtin_amdgcn_mfma_f32_16x16x32_bf16(af[mi], bfr[ni], acc[mi][ni], 0, 0, 0);
        }
        __syncthreads();
    }

    // ---- epilogue: D layout col = lane&15, row = quad*4 + r (m89-verified) ----
    // scalar Q/K stores for ng < 4096 (fragment-uniform branch: boundary 16-aligned)
#pragma unroll
    for (int mi = 0; mi < 4; mi++) {
#pragma unroll
        for (int ni = 0; ni < 6; ni++) {
            int ng = n0 + wn * 96 + ni * 16 + l16;
            if (ng < 4096) {
                int which = ng >> 11;          // 0=Q 1=K
                int rem = ng & 2047;
                int h = rem >> 7, d = rem & 127;
#pragma unroll
                for (int r = 0; r < 4; r++) {
                    int mg = m0 + wm * 64 + mi * 16 + quad * 4 + r;
                    float val = acc[mi][ni][r];
                    int b = mg >> 11, s = mg & 2047;
                    if (which == 0)
                        q[((size_t)((b * NH_ + h) * S_ + s)) * HD_ + d] = f2bf(val * SL2f);
                    else
                        k[((size_t)((b * NH_ + h) * S_ + s)) * HD_ + d] = f2bf(val);
                }
            }
        }
    }
    // V columns (ng >= 4096): bounce through LDS (swizzled), b128 stores to VT[b,h,d,s]
    if (n0 + 192 > 4096) {
        __syncthreads();
#pragma unroll
        for (int mi = 0; mi < 4; mi++) {
#pragma unroll
            for (int ni = 0; ni < 6; ni++) {
                int nl = wn * 96 + ni * 16 + l16;            // 0..191
                if (n0 + nl >= 4096) {
#pragma unroll
                    for (int r = 0; r < 4; r++) {
                        int ml = wm * 64 + mi * 16 + quad * 4 + r;  // 0..127
                        sm[nl * 128 + (((ml >> 3) ^ (nl & 15)) * 8) + (ml & 7)] = f2bf(acc[mi][ni][r]);
                    }
                }
            }
        }
        __syncthreads();
        int b = m0 >> 11, s0 = m0 & 2047;
        int vstart = (n0 < 4096) ? (4096 - n0) : 0;   // 64 for the mixed tile, else 0
        int nch = (192 - vstart) * 16;
#pragma unroll
        for (int i = 0; i < 12; i++) {
            int cu = tid + i * 256;
            if (cu < nch) {
                int nl = vstart + (cu >> 4), mc = cu & 15;
                int4 val = *(const int4*)&sm[nl * 128 + ((mc ^ (nl & 15)) * 8)];
                int ngl = (n0 + nl) - 4096;
                int h = ngl >> 7, d = ngl & 127;
                *(int4*)&v[((size_t)((b * NH_ + h) * HD_ + d)) * S_ + s0 + mc * 8] = val;
            }
        }
    }
}

// ---------------- output GEMM (round-0 proven 128x128 structure) --------
// C[M,N] = A[M,K] @ Bt[N,K]^T, fp32 row-major output.
__global__ __launch_bounds__(256, 2) void gemm_out(
        const u16* __restrict__ A, const u16* __restrict__ Bt, float* __restrict__ Cout,
        int M, int N, int K) {
    __shared__ u16 sm[2 * 128 * 64];   // As | Bs
    u16* As = sm;
    u16* Bs = sm + 128 * 64;
    int tid = threadIdx.x;
    int w = tid >> 6, lane = tid & 63, quad = lane >> 4, l16 = lane & 15;
    int wm = w >> 1, wn = w & 1;
    int m0 = blockIdx.y * 128, n0 = blockIdx.x * 128;

    f32x4 acc[4][4];
#pragma unroll
    for (int mi = 0; mi < 4; mi++)
#pragma unroll
        for (int ni = 0; ni < 4; ni++)
            acc[mi][ni] = (f32x4){0.f, 0.f, 0.f, 0.f};

    for (int k0 = 0; k0 < K; k0 += 64) {
        const u16* ga = A + (size_t)m0 * K + k0;
        const u16* gb = Bt + (size_t)n0 * K + k0;
#pragma unroll
        for (int j = 0; j < 4; j++) {
            int base = (j * 4 + w) * 64;
            int p = base + lane;
            int row = p >> 3;
            int c = (p & 7) ^ (row & 7);
            gl_lds16(&ga[(size_t)row * K + c * 8], &As[base * 8]);
            gl_lds16(&gb[(size_t)row * K + c * 8], &Bs[base * 8]);
        }
        __syncthreads();
#pragma unroll
        for (int ks = 0; ks < 2; ks++) {
            bf16x8 af[4], bfr[4];
#pragma unroll
            for (int mi = 0; mi < 4; mi++) {
                int row = wm * 64 + mi * 16 + l16;
                af[mi] = *(const bf16x8*)&As[row * 64 + (((ks * 4 + quad) ^ (row & 7)) * 8)];
            }
#pragma unroll
            for (int ni = 0; ni < 4; ni++) {
                int row = wn * 64 + ni * 16 + l16;
                bfr[ni] = *(const bf16x8*)&Bs[row * 64 + (((ks * 4 + quad) ^ (row & 7)) * 8)];
            }
#pragma unroll
            for (int mi = 0; mi < 4; mi++)
#pragma unroll
                for (int ni = 0; ni < 4; ni++)
                    acc[mi][ni] = __builtin_amdgcn_mfma_f32_16x16x32_bf16(af[mi], bfr[ni], acc[mi][ni], 0, 0, 0);
        }
        __syncthreads();
    }

#pragma unroll
    for (int mi = 0; mi < 4; mi++) {
#pragma unroll
        for (int ni = 0; ni < 4; ni++) {
            int ng = n0 + wn * 64 + ni * 16 + l16;
#pragma unroll
            for (int r = 0; r < 4; r++) {
                int mg = m0 + wm * 64 + mi * 16 + quad * 4 + r;
                Cout[(size_t)mg * N + ng] = acc[mi][ni][r];
            }
        }
    }
}

// ---------------- causal flash attention ----------------
// Paired q-tiles: 512 blocks, block (b,h,pair) does qt=pair then qt=31-pair -> uniform 33 iters.
// S^T = K·Q^T trick: P stays in registers (C-layout == B-frag of 16x16x16 MFMA).
// Barrier plan: phase1 = QK only (mid barrier drains lgkm only); K(t+1),V(t+1) DMA issued
// AFTER mid barrier, hidden under softmax+PV, drained at next top barrier. K,V both dbuf.
// LDS = 2*16K + 2*16K = 64KB -> exactly 2 blocks/CU for the 512-block grid.
__global__ __launch_bounds__(256, 2) void flash_kernel(
        const u16* __restrict__ Q, const u16* __restrict__ Kb,
        const u16* __restrict__ VT, u16* __restrict__ Ctx) {
    __shared__ u16 Ks[2][64 * 128];  // [kv][d], chunk c at c ^ (kv&15)
    __shared__ u16 Vs[2][128 * 64];  // [d][kv], chunk c at c ^ (d&7)
    int tid = threadIdx.x;
    int w = tid >> 6, lane = tid & 63, quad = lane >> 4, l16 = lane & 15;

    int id = blockIdx.x;
    int bh = id & 31;
    int b = bh >> 4, h = bh & 15;
    int pair = id >> 5;              // 0..15
    int qts = pair, qtl = 31 - pair;
    int n0 = qts + 1;                // iters in segment 0; total always 33

    size_t bhoff = ((size_t)b * NH_ + h) * S_ * HD_;
    const u16* Qp = Q + bhoff;
    const u16* Kp = Kb + bhoff;
    const u16* Vp = VT + bhoff;      // [d][s]

    auto stageK = [&](int t, int buf) {
        int kv0 = ((t >= n0) ? (t - n0) : t) * 64;
#pragma unroll
        for (int j = 0; j < 4; j++) {
            int base = (j * 4 + w) * 64;
            int p = base + lane;
            int row = p >> 4;
            int c = (p & 15) ^ (row & 15);
            gl_lds16(&Kp[(size_t)(kv0 + row) * HD_ + c * 8], &Ks[buf][base * 8]);
        }
    };
    auto stageV = [&](int t, int buf) {
        int kv0 = ((t >= n0) ? (t - n0) : t) * 64;
#pragma unroll
        for (int j = 0; j < 4; j++) {
            int base = (j * 4 + w) * 64;
            int p = base + lane;
            int row = p >> 3;
            int c = (p & 7) ^ (row & 7);
            gl_lds16(&Vp[(size_t)row * S_ + kv0 + c * 8], &Vs[buf][base * 8]);
        }
    };

    int q0 = qts * 64;
    int qg = q0 + w * 16 + l16;      // this lane's q row (S^T: lane = q column)
    bf16x8 qf[4];
#pragma unroll
    for (int ks = 0; ks < 4; ks++)
        qf[ks] = *(const bf16x8*)&Qp[(size_t)qg * HD_ + ks * 32 + quad * 8];

    float l_part = 0.f;
    f32x4 ao[8];                     // O^T acc: rows d=dt*16+quad*4+r, col q=l16
#pragma unroll
    for (int dt = 0; dt < 8; dt++) ao[dt] = (f32x4){0.f, 0.f, 0.f, 0.f};

    auto epilogue = [&]() {
        float l = l_part;
        l += __shfl_xor(l, 16);
        l += __shfl_xor(l, 32);
        float inv = 1.0f / l;
        size_t base = ((size_t)b * S_ + qg) * H_ + h * HD_;
#pragma unroll
        for (int dt = 0; dt < 8; dt++) {
            u16 o0 = f2bf(ao[dt][0] * inv), o1 = f2bf(ao[dt][1] * inv);
            u16 o2 = f2bf(ao[dt][2] * inv), o3 = f2bf(ao[dt][3] * inv);
            uint2 st;
            st.x = (uint32_t)o0 | ((uint32_t)o1 << 16);
            st.y = (uint32_t)o2 | ((uint32_t)o3 << 16);
            *(uint2*)&Ctx[base + dt * 16 + quad * 4] = st;
        }
    };

    stageK(0, 0);
    stageV(0, 0);

    for (int t = 0; t < 33; t++) {
        if (t == n0) {               // segment switch (PV of seg0 finished last iter)
            epilogue();
            q0 = qtl * 64;
            qg = q0 + w * 16 + l16;
#pragma unroll
            for (int ks = 0; ks < 4; ks++)
                qf[ks] = *(const bf16x8*)&Qp[(size_t)qg * HD_ + ks * 32 + quad * 8];
            l_part = 0.f;
#pragma unroll
            for (int dt = 0; dt < 8; dt++) ao[dt] = (f32x4){0.f, 0.f, 0.f, 0.f};
        }
        int buf = t & 1;
        __syncthreads();             // A: drains K(t),V(t) DMA (issued last phase-2)

        // --- phase 1: S^T = K·Q^T only (no vmem issued -> cheap mid barrier) ---
        f32x4 sc[4];
#pragma unroll
        for (int nt = 0; nt < 4; nt++) {
            sc[nt] = (f32x4){0.f, 0.f, 0.f, 0.f};
            int row = nt * 16 + l16;
#pragma unroll
            for (int ks = 0; ks < 4; ks++) {
                bf16x8 kf = *(const bf16x8*)&Ks[buf][row * 128 + (((ks * 4 + quad) ^ (row & 15)) * 8)];
                sc[nt] = __builtin_amdgcn_mfma_f32_16x16x32_bf16(kf, qf[ks], sc[nt], 0, 0, 0);
            }
        }

        __syncthreads();             // B: lgkm-only drain

        // --- phase 2: prefetch next K,V (hidden under softmax+PV, drained at next A) ---
        if (t + 1 < 33) {
            stageK(t + 1, buf ^ 1);
            stageV(t + 1, buf ^ 1);
        }

        // --- softmax in registers; pack P^T as 16x16x16 B-fragments ---
        bool diag = (t == n0 - 1) || (t == 32);
        U2S4 pk[4];
        if (!diag) {
#pragma unroll
            for (int nt = 0; nt < 4; nt++) {
                float p0 = exp2f(sc[nt][0]), p1 = exp2f(sc[nt][1]);
                float p2 = exp2f(sc[nt][2]), p3 = exp2f(sc[nt][3]);
                l_part += (p0 + p1) + (p2 + p3);
                pk[nt].u.x = pk_bf16(p0, p1);
                pk[nt].u.y = pk_bf16(p2, p3);
            }
        } else {                     // diagonal tile: causal mask (kv index vs qg)
            int kvb = q0 + quad * 4; // diag tile: kv0 == q0
#pragma unroll
            for (int nt = 0; nt < 4; nt++) {
                int kv = kvb + nt * 16;
                float p0 = (kv + 0 > qg) ? 0.f : exp2f(sc[nt][0]);
                float p1 = (kv + 1 > qg) ? 0.f : exp2f(sc[nt][1]);
                float p2 = (kv + 2 > qg) ? 0.f : exp2f(sc[nt][2]);
                float p3 = (kv + 3 > qg) ? 0.f : exp2f(sc[nt][3]);
                l_part += (p0 + p1) + (p2 + p3);
                pk[nt].u.x = pk_bf16(p0, p1);
                pk[nt].u.y = pk_bf16(p2, p3);
            }
        }

        // --- O^T += V^T·P^T : A=Vs[d][kv], B=pk (registers) ---
#pragma unroll
        for (int kt = 0; kt < 4; kt++) {
#pragma unroll
            for (int dt = 0; dt < 8; dt++) {
                int d = dt * 16 + l16;
                int c = kt * 2 + (quad >> 1);
                s4 va = *(const s4*)&Vs[buf][d * 64 + ((c ^ (d & 7)) * 8) + (quad & 1) * 4];
                ao[dt] = __builtin_amdgcn_mfma_f32_16x16x16bf16_1k(va, pk[kt].s, ao[dt], 0, 0, 0);
            }
        }
    }
    epilogue();
}

extern "C" void kernel_launch(void* const* d_in, const int* in_sizes, int n_in,
                              void* d_out, int out_size, void* d_ws, size_t ws_size,
                              hipStream_t stream) {
    const float* x  = (const float*)d_in[0];
    const float* Wq = (const float*)d_in[1];
    const float* Wk = (const float*)d_in[2];
    const float* Wv = (const float*)d_in[3];
    const float* Wo = (const float*)d_in[4];
    float* out = (float*)d_out;

    const size_t MB = 1024 * 1024;
    char* ws = (char*)d_ws;
    u16* Xb    = (u16*)(ws);            // 16 MB : x bf16 [4096,2048]
    u16* WqkvT = (u16*)(ws + 16 * MB);  // 24 MB : [6144,2048] (Wq^T;Wk^T;Wv^T)
    u16* WoT   = (u16*)(ws + 40 * MB);  //  8 MB
    u16* Qb    = (u16*)(ws + 48 * MB);  // 16 MB : [B,NH,S,HD], pre-scaled by SL2f
    u16* Kbuf  = (u16*)(ws + 64 * MB);  // 16 MB : [B,NH,S,HD]
    u16* VT    = (u16*)(ws + 80 * MB);  // 16 MB : [B,NH,HD,S]
    u16* Ctx   = (u16*)(ws + 96 * MB);  // 16 MB : [4096,2048]

    prep_kernel<<<dim3(64, 64, 5), dim3(32, 8), 0, stream>>>(x, Wq, Wk, Wv, Wo, Xb, WqkvT, WoT);
    // fat-wave-tile QKV GEMM: 32x32 = 1024 blocks @ 2 blk/CU = exactly 2 rounds
    gemm_qkv<<<dim3(32, 32), 256, 0, stream>>>(Xb, WqkvT, Qb, Kbuf, VT, 4096, 6144, 2048);
    flash_kernel<<<512, 256, 0, stream>>>(Qb, Kbuf, VT, Ctx);
    // output GEMM: round-0 proven 128^2 structure, 16x32 = 512 blocks
    gemm_out<<<dim3(16, 32), 256, 0, stream>>>(Ctx, WoT, out, 4096, 2048, 2048);
}